// Round 1
// baseline (113.436 us; speedup 1.0000x reference)
//
#include <hip/hip_runtime.h>

// MaxChamferDistance: x[16,4096,3], y[16,4096,3] f32 -> scalar f32
// out = mean_b max( mean_n min_m ||x_bn - y_bm||^2 , mean_m min_n ||.||^2 )
//
// Compute-bound fp32 (no fp32 MFMA on CDNA4). Strategy:
//   kernel 1: 256 blocks = 2 dirs x 16 batches x 8 chunks of 512 "own" points.
//             Stage full "other" cloud in LDS as float4(p0,p1,p2,||p||^2).
//             Each thread owns 2 points, loops all 4096 other points
//             (broadcast ds_read_b128), tracks running min via the
//             ||x||^2+||y||^2-2<x,y> expansion (matches reference numerics).
//             Block-reduces the sum of mins -> partials[bid] (deterministic).
//   kernel 2: single block folds 256 partials -> scalar.

#define BATCH   16
#define NPTS    4096
#define CHUNK_PTS 512                  // points per block (2 per thread)
#define CHUNKS  (NPTS / CHUNK_PTS)     // 8
#define NBLOCKS (2 * BATCH * CHUNKS)   // 256

__global__ __launch_bounds__(256) void chamfer_partial(
    const float* __restrict__ x, const float* __restrict__ y,
    float* __restrict__ partials) {
  __shared__ float4 yl[NPTS];          // 64 KB: (p0,p1,p2,||p||^2)

  const int bid = blockIdx.x;
  const int dir = bid >> 7;            // 0: x->y, 1: y->x
  const int rem = bid & 127;
  const int b   = rem >> 3;
  const int c   = rem & 7;

  const float* own   = (dir == 0 ? x : y) + (size_t)b * NPTS * 3;
  const float* other = (dir == 0 ? y : x) + (size_t)b * NPTS * 3;

  // stage "other" cloud into LDS with precomputed squared norm
  for (int i = threadIdx.x; i < NPTS; i += 256) {
    float a0 = other[i * 3 + 0];
    float a1 = other[i * 3 + 1];
    float a2 = other[i * 3 + 2];
    yl[i] = make_float4(a0, a1, a2, fmaf(a2, a2, fmaf(a1, a1, a0 * a0)));
  }
  __syncthreads();

  // each thread owns 2 points of the "own" cloud
  const int p0 = c * CHUNK_PTS + threadIdx.x;
  const int p1 = p0 + 256;
  const float xa0 = own[p0 * 3 + 0], xa1 = own[p0 * 3 + 1], xa2 = own[p0 * 3 + 2];
  const float xb0 = own[p1 * 3 + 0], xb1 = own[p1 * 3 + 1], xb2 = own[p1 * 3 + 2];
  const float sqa = fmaf(xa2, xa2, fmaf(xa1, xa1, xa0 * xa0));
  const float sqb = fmaf(xb2, xb2, fmaf(xb1, xb1, xb0 * xb0));

  float ma = 1e30f, mb = 1e30f;
  #pragma unroll 8
  for (int m = 0; m < NPTS; ++m) {
    float4 q = yl[m];                              // broadcast ds_read_b128
    float dota = fmaf(xa2, q.z, fmaf(xa1, q.y, xa0 * q.x));
    float da   = fmaf(-2.0f, dota, sqa + q.w);
    ma = fminf(ma, da);
    float dotb = fmaf(xb2, q.z, fmaf(xb1, q.y, xb0 * q.x));
    float db   = fmaf(-2.0f, dotb, sqb + q.w);
    mb = fminf(mb, db);
  }

  // deterministic block reduction of sum-of-mins
  float s = ma + mb;
  #pragma unroll
  for (int off = 32; off > 0; off >>= 1) s += __shfl_down(s, off, 64);

  __syncthreads();                    // done reading yl; reuse for reduction
  float* red = (float*)yl;
  const int lane = threadIdx.x & 63, wid = threadIdx.x >> 6;
  if (lane == 0) red[wid] = s;
  __syncthreads();
  if (threadIdx.x == 0)
    partials[bid] = (red[0] + red[1]) + (red[2] + red[3]);
}

__global__ __launch_bounds__(256) void chamfer_final(
    const float* __restrict__ partials, float* __restrict__ out) {
  __shared__ float sm[NBLOCKS];
  __shared__ float dist[2 * BATCH];
  const int t = threadIdx.x;
  sm[t] = partials[t];
  __syncthreads();
  if (t < 2 * BATCH) {                 // t = dir*16 + b
    float s = 0.0f;
    #pragma unroll
    for (int k = 0; k < CHUNKS; ++k) s += sm[t * CHUNKS + k];
    dist[t] = s * (1.0f / (float)NPTS);
  }
  __syncthreads();
  if (t == 0) {
    float acc = 0.0f;
    #pragma unroll
    for (int b = 0; b < BATCH; ++b) acc += fmaxf(dist[b], dist[BATCH + b]);
    out[0] = acc * (1.0f / (float)BATCH);
  }
}

extern "C" void kernel_launch(void* const* d_in, const int* in_sizes, int n_in,
                              void* d_out, int out_size, void* d_ws, size_t ws_size,
                              hipStream_t stream) {
  const float* x = (const float*)d_in[0];
  const float* y = (const float*)d_in[1];
  float* out = (float*)d_out;
  float* partials = (float*)d_ws;      // 256 floats

  chamfer_partial<<<NBLOCKS, 256, 0, stream>>>(x, y, partials);
  chamfer_final<<<1, 256, 0, stream>>>(partials, out);
}

// Round 2
// 60.713 us; speedup vs baseline: 1.8684x; 1.8684x over previous
//
#include <hip/hip_runtime.h>

// MaxChamferDistance: x[16,4096,3], y[16,4096,3] f32 -> scalar f32
//
// Round-2 plan (see journal): fp32-VALU-bound, previously 1 wave/SIMD and
// 6 VALU/pair. Now:
//  - LDS stores q' = (-2*p, ||p||^2): per pair cost = 3 chained fma
//    (t = fma(x0,qx', fma(x1,qy', fma(x2,qz', w)))), ||x||^2 hoisted out
//    of the min (min(s+t) = s+min(t)); min3-friendly pairing.
//  - Other cloud split into SEG=2 segments of 2048 pts (one 32KB LDS tile
//    per block, no tile loop) -> 1024 blocks x 128 thr = 2 waves/SIMD.
//  - Per-own-point partial mins -> ws (1MB); combine kernel mins across
//    segments + sums per (dir,b); final kernel does mean/max/mean.
// All reductions fixed-order -> deterministic across graph replays.

#define BATCH   16
#define NPTS    4096
#define SEG     2
#define SEGPTS  (NPTS / SEG)          // 2048
#define THREADS1 128
#define POWN    2
#define CHUNK   (THREADS1 * POWN)     // 256 own points per block
#define CHUNKS  (NPTS / CHUNK)        // 16
#define DB      (2 * BATCH)           // 32 (dir, batch) pairs
#define NB1     (SEG * DB * CHUNKS)   // 1024 blocks
#define PM_FLOATS (SEG * DB * NPTS)   // 262144 floats = 1 MB

__global__ __launch_bounds__(THREADS1) void chamfer_seg(
    const float* __restrict__ x, const float* __restrict__ y,
    float* __restrict__ pm) {
  __shared__ float4 ql[SEGPTS];       // 32 KB: (-2p0,-2p1,-2p2,||p||^2)

  const int bid = blockIdx.x;
  const int s   = bid >> 9;           // segment (512 blocks per segment)
  const int rem = bid & 511;
  const int db  = rem >> 4;           // dir*16 + b
  const int c   = rem & 15;           // own-point chunk
  const int dir = db >> 4;
  const int b   = db & 15;

  const float* own   = (dir == 0 ? x : y) + (size_t)b * NPTS * 3;
  const float* other = (dir == 0 ? y : x) + (size_t)b * NPTS * 3;
  const float* sp    = other + (size_t)s * SEGPTS * 3;

  for (int i = threadIdx.x; i < SEGPTS; i += THREADS1) {
    float a0 = sp[i * 3 + 0];
    float a1 = sp[i * 3 + 1];
    float a2 = sp[i * 3 + 2];
    float w  = fmaf(a2, a2, fmaf(a1, a1, a0 * a0));
    ql[i] = make_float4(-2.0f * a0, -2.0f * a1, -2.0f * a2, w);
  }
  __syncthreads();

  const int p0 = c * CHUNK + threadIdx.x;
  const int p1 = p0 + THREADS1;
  const float xa0 = own[p0 * 3 + 0], xa1 = own[p0 * 3 + 1], xa2 = own[p0 * 3 + 2];
  const float xb0 = own[p1 * 3 + 0], xb1 = own[p1 * 3 + 1], xb2 = own[p1 * 3 + 2];
  const float sqa = fmaf(xa2, xa2, fmaf(xa1, xa1, xa0 * xa0));
  const float sqb = fmaf(xb2, xb2, fmaf(xb1, xb1, xb0 * xb0));

  float ma = 1e30f, mb = 1e30f;
  #pragma unroll 4
  for (int m = 0; m < SEGPTS; m += 2) {
    float4 u = ql[m];                 // broadcast ds_read_b128, conflict-free
    float4 v = ql[m + 1];
    float ta0 = fmaf(xa0, u.x, fmaf(xa1, u.y, fmaf(xa2, u.z, u.w)));
    float ta1 = fmaf(xa0, v.x, fmaf(xa1, v.y, fmaf(xa2, v.z, v.w)));
    ma = fminf(ma, fminf(ta0, ta1));  // v_min3_f32 candidate
    float tb0 = fmaf(xb0, u.x, fmaf(xb1, u.y, fmaf(xb2, u.z, u.w)));
    float tb1 = fmaf(xb0, v.x, fmaf(xb1, v.y, fmaf(xb2, v.z, v.w)));
    mb = fminf(mb, fminf(tb0, tb1));
  }

  float* dst = pm + (size_t)s * DB * NPTS + (size_t)db * NPTS + c * CHUNK;
  dst[threadIdx.x]            = sqa + ma;   // coalesced partial-min writes
  dst[threadIdx.x + THREADS1] = sqb + mb;
}

__global__ __launch_bounds__(256) void chamfer_combine(
    const float* __restrict__ pm, float* __restrict__ dist) {
  const int db = blockIdx.x;                // one (dir,b) per block
  const float* q0 = pm + (size_t)db * NPTS;
  const float* q1 = q0 + (size_t)DB * NPTS; // segment 1
  float s = 0.0f;
  for (int i = threadIdx.x; i < NPTS; i += 256)
    s += fminf(q0[i], q1[i]);
  #pragma unroll
  for (int off = 32; off > 0; off >>= 1) s += __shfl_down(s, off, 64);
  __shared__ float red[4];
  const int lane = threadIdx.x & 63, wid = threadIdx.x >> 6;
  if (lane == 0) red[wid] = s;
  __syncthreads();
  if (threadIdx.x == 0)
    dist[db] = ((red[0] + red[1]) + (red[2] + red[3])) * (1.0f / (float)NPTS);
}

__global__ void chamfer_final(const float* __restrict__ dist,
                              float* __restrict__ out) {
  if (threadIdx.x == 0) {
    float acc = 0.0f;
    #pragma unroll
    for (int b = 0; b < BATCH; ++b) acc += fmaxf(dist[b], dist[BATCH + b]);
    out[0] = acc * (1.0f / (float)BATCH);
  }
}

// ---------- fallback (round-1 proven path, used only if ws too small) ------
__global__ __launch_bounds__(256) void chamfer_partial_fb(
    const float* __restrict__ x, const float* __restrict__ y,
    float* __restrict__ partials) {
  __shared__ float4 yl[NPTS];
  const int bid = blockIdx.x;
  const int dir = bid >> 7;
  const int rem = bid & 127;
  const int b   = rem >> 3;
  const int c   = rem & 7;
  const float* own   = (dir == 0 ? x : y) + (size_t)b * NPTS * 3;
  const float* other = (dir == 0 ? y : x) + (size_t)b * NPTS * 3;
  for (int i = threadIdx.x; i < NPTS; i += 256) {
    float a0 = other[i * 3 + 0], a1 = other[i * 3 + 1], a2 = other[i * 3 + 2];
    float w  = fmaf(a2, a2, fmaf(a1, a1, a0 * a0));
    yl[i] = make_float4(-2.0f * a0, -2.0f * a1, -2.0f * a2, w);
  }
  __syncthreads();
  const int p0 = c * 512 + threadIdx.x;
  const int p1 = p0 + 256;
  const float xa0 = own[p0 * 3], xa1 = own[p0 * 3 + 1], xa2 = own[p0 * 3 + 2];
  const float xb0 = own[p1 * 3], xb1 = own[p1 * 3 + 1], xb2 = own[p1 * 3 + 2];
  const float sqa = fmaf(xa2, xa2, fmaf(xa1, xa1, xa0 * xa0));
  const float sqb = fmaf(xb2, xb2, fmaf(xb1, xb1, xb0 * xb0));
  float ma = 1e30f, mb = 1e30f;
  #pragma unroll 8
  for (int m = 0; m < NPTS; ++m) {
    float4 q = yl[m];
    ma = fminf(ma, fmaf(xa0, q.x, fmaf(xa1, q.y, fmaf(xa2, q.z, q.w))));
    mb = fminf(mb, fmaf(xb0, q.x, fmaf(xb1, q.y, fmaf(xb2, q.z, q.w))));
  }
  float s = (sqa + ma) + (sqb + mb);
  #pragma unroll
  for (int off = 32; off > 0; off >>= 1) s += __shfl_down(s, off, 64);
  __syncthreads();
  float* red = (float*)yl;
  const int lane = threadIdx.x & 63, wid = threadIdx.x >> 6;
  if (lane == 0) red[wid] = s;
  __syncthreads();
  if (threadIdx.x == 0)
    partials[bid] = (red[0] + red[1]) + (red[2] + red[3]);
}

__global__ __launch_bounds__(256) void chamfer_final_fb(
    const float* __restrict__ partials, float* __restrict__ out) {
  __shared__ float sm[256];
  __shared__ float dist[DB];
  const int t = threadIdx.x;
  sm[t] = partials[t];
  __syncthreads();
  if (t < DB) {
    float s = 0.0f;
    #pragma unroll
    for (int k = 0; k < 8; ++k) s += sm[t * 8 + k];
    dist[t] = s * (1.0f / (float)NPTS);
  }
  __syncthreads();
  if (t == 0) {
    float acc = 0.0f;
    #pragma unroll
    for (int b = 0; b < BATCH; ++b) acc += fmaxf(dist[b], dist[BATCH + b]);
    out[0] = acc * (1.0f / (float)BATCH);
  }
}

extern "C" void kernel_launch(void* const* d_in, const int* in_sizes, int n_in,
                              void* d_out, int out_size, void* d_ws, size_t ws_size,
                              hipStream_t stream) {
  const float* x = (const float*)d_in[0];
  const float* y = (const float*)d_in[1];
  float* out = (float*)d_out;

  if (ws_size >= (size_t)(PM_FLOATS + DB) * sizeof(float)) {
    float* pm   = (float*)d_ws;
    float* dist = pm + PM_FLOATS;
    chamfer_seg<<<NB1, THREADS1, 0, stream>>>(x, y, pm);
    chamfer_combine<<<DB, 256, 0, stream>>>(pm, dist);
    chamfer_final<<<1, 64, 0, stream>>>(dist, out);
  } else {
    float* partials = (float*)d_ws;   // 256 floats
    chamfer_partial_fb<<<256, 256, 0, stream>>>(x, y, partials);
    chamfer_final_fb<<<1, 256, 0, stream>>>(partials, out);
  }
}

// Round 3
// 59.573 us; speedup vs baseline: 1.9041x; 1.0191x over previous
//
#include <hip/hip_runtime.h>

// MaxChamferDistance: x[16,4096,3], y[16,4096,3] f32 -> scalar f32
//
// Round-3: round-2 was latency-bound (2 waves/SIMD, grid-limited; VALU ~44%
// real, DS ~30-60%). Changes:
//  - SEG=8 segments of 512 other-points (8KB LDS) -> 2048 blocks = 8/CU
//    = 16 waves/CU = 4 waves/SIMD (2x occupancy).
//  - POWN=4 own points per thread -> each broadcast ds_read_b128 feeds 4
//    pairs (DS instruction count halved).
//  - Cross-segment min via atomicMin on monotone-uint-encoded floats
//    (float-min is order-independent -> deterministic across replays).
//    ws: 512KB pm + 32 dist floats (fits the >=1MB ws proven in round 2).
// Inner loop cost unchanged: 3 fma/pair + min3 per 2 pairs.

#define BATCH   16
#define NPTS    4096
#define DB      (2 * BATCH)           // 32 (dir,batch) pairs
#define SEG     8
#define SEGPTS  (NPTS / SEG)          // 512
#define THREADS1 128
#define POWN    4
#define CHUNK   (THREADS1 * POWN)     // 512 own points per block
#define CHUNKS  (NPTS / CHUNK)        // 8
#define NB1     (SEG * DB * CHUNKS)   // 2048 blocks
#define PM_U32  (DB * NPTS)           // 131072 entries = 512 KB

__device__ __forceinline__ unsigned enc_f32(float f) {
  unsigned u = __float_as_uint(f);
  return (u & 0x80000000u) ? ~u : (u | 0x80000000u);   // monotone in f
}
__device__ __forceinline__ float dec_f32(unsigned u) {
  return __uint_as_float((u & 0x80000000u) ? (u ^ 0x80000000u) : ~u);
}

__global__ __launch_bounds__(256) void chamfer_init(unsigned* __restrict__ pm) {
  pm[blockIdx.x * 256 + threadIdx.x] = 0xFFFFFFFFu;    // enc(+max)
}

__global__ __launch_bounds__(THREADS1) void chamfer_seg(
    const float* __restrict__ x, const float* __restrict__ y,
    unsigned* __restrict__ pm) {
  __shared__ float4 ql[SEGPTS];       // 8 KB: (-2p0,-2p1,-2p2,||p||^2)

  const int bid = blockIdx.x;
  const int s   = bid >> 8;           // segment (DB*CHUNKS = 256 blocks each)
  const int rem = bid & 255;
  const int db  = rem >> 3;           // dir*16 + b
  const int c   = rem & 7;            // own-point chunk
  const int dir = db >> 4;
  const int b   = db & 15;

  const float* own   = (dir == 0 ? x : y) + (size_t)b * NPTS * 3;
  const float* other = (dir == 0 ? y : x) + (size_t)b * NPTS * 3;
  const float* sp    = other + (size_t)s * SEGPTS * 3;

  for (int i = threadIdx.x; i < SEGPTS; i += THREADS1) {
    float a0 = sp[i * 3 + 0];
    float a1 = sp[i * 3 + 1];
    float a2 = sp[i * 3 + 2];
    float w  = fmaf(a2, a2, fmaf(a1, a1, a0 * a0));
    ql[i] = make_float4(-2.0f * a0, -2.0f * a1, -2.0f * a2, w);
  }
  __syncthreads();

  // 4 own points per thread
  const int base = c * CHUNK + threadIdx.x;
  float x0[POWN], x1[POWN], x2[POWN], sq[POWN], mn[POWN];
  #pragma unroll
  for (int k = 0; k < POWN; ++k) {
    const int p = base + k * THREADS1;
    x0[k] = own[p * 3 + 0];
    x1[k] = own[p * 3 + 1];
    x2[k] = own[p * 3 + 2];
    sq[k] = fmaf(x2[k], x2[k], fmaf(x1[k], x1[k], x0[k] * x0[k]));
    mn[k] = 1e30f;
  }

  #pragma unroll 4
  for (int m = 0; m < SEGPTS; m += 2) {
    float4 u = ql[m];                 // broadcast ds_read_b128
    float4 v = ql[m + 1];
    #pragma unroll
    for (int k = 0; k < POWN; ++k) {
      float t0 = fmaf(x0[k], u.x, fmaf(x1[k], u.y, fmaf(x2[k], u.z, u.w)));
      float t1 = fmaf(x0[k], v.x, fmaf(x1[k], v.y, fmaf(x2[k], v.z, v.w)));
      mn[k] = fminf(mn[k], fminf(t0, t1));   // v_min3_f32 candidate
    }
  }

  unsigned* dst = pm + (size_t)db * NPTS;
  #pragma unroll
  for (int k = 0; k < POWN; ++k)
    atomicMin(&dst[base + k * THREADS1], enc_f32(sq[k] + mn[k]));
}

__global__ __launch_bounds__(256) void chamfer_combine(
    const unsigned* __restrict__ pm, float* __restrict__ dist) {
  const int db = blockIdx.x;                 // one (dir,b) per block
  const unsigned* q = pm + (size_t)db * NPTS;
  float s = 0.0f;
  #pragma unroll
  for (int i = threadIdx.x; i < NPTS; i += 256)
    s += dec_f32(q[i]);
  #pragma unroll
  for (int off = 32; off > 0; off >>= 1) s += __shfl_down(s, off, 64);
  __shared__ float red[4];
  const int lane = threadIdx.x & 63, wid = threadIdx.x >> 6;
  if (lane == 0) red[wid] = s;
  __syncthreads();
  if (threadIdx.x == 0)
    dist[db] = ((red[0] + red[1]) + (red[2] + red[3])) * (1.0f / (float)NPTS);
}

__global__ void chamfer_final(const float* __restrict__ dist,
                              float* __restrict__ out) {
  if (threadIdx.x == 0) {
    float acc = 0.0f;
    #pragma unroll
    for (int b = 0; b < BATCH; ++b) acc += fmaxf(dist[b], dist[BATCH + b]);
    out[0] = acc * (1.0f / (float)BATCH);
  }
}

extern "C" void kernel_launch(void* const* d_in, const int* in_sizes, int n_in,
                              void* d_out, int out_size, void* d_ws, size_t ws_size,
                              hipStream_t stream) {
  const float* x = (const float*)d_in[0];
  const float* y = (const float*)d_in[1];
  float* out = (float*)d_out;

  unsigned* pm = (unsigned*)d_ws;            // 131072 u32 = 512 KB
  float* dist  = (float*)(pm + PM_U32);      // 32 floats

  chamfer_init<<<PM_U32 / 256, 256, 0, stream>>>(pm);
  chamfer_seg<<<NB1, THREADS1, 0, stream>>>(x, y, pm);
  chamfer_combine<<<DB, 256, 0, stream>>>(pm, dist);
  chamfer_final<<<1, 64, 0, stream>>>(dist, out);
}